// Round 13
// baseline (1321.413 us; speedup 1.0000x reference)
//
#include <hip/hip_runtime.h>

#define DDIM 128
#define HDIM 256
#define BQ   4
#define NN   4096
#define RTOT (BQ*NN)

typedef short short8 __attribute__((ext_vector_type(8)));
typedef short short4v __attribute__((ext_vector_type(4)));
typedef float f32x16 __attribute__((ext_vector_type(16)));

__device__ inline unsigned short f2bf(float f) {
    unsigned int u = __float_as_uint(f);
    unsigned int r = (u + 0x7fffu + ((u >> 16) & 1u)) >> 16;
    return (unsigned short)r;
}
__device__ inline float bf2f(unsigned short h) {
    return __uint_as_float(((unsigned int)h) << 16);
}

#define MFMA32(a, b, c) __builtin_amdgcn_mfma_f32_32x32x16_bf16(a, b, c, 0, 0, 0)

// ---------------- weight packer (unchanged) ----------------
__global__ void pack_w_kernel(const float* __restrict__ W, int N,
                              unsigned short* __restrict__ ph, unsigned short* __restrict__ pl) {
    int l = threadIdx.x, l31 = l & 31, lh = l >> 5;
    int nt = N >> 5;
    int t = blockIdx.x / nt, c = blockIdx.x % nt;
    short8 hv, lv;
#pragma unroll
    for (int j = 0; j < 8; ++j) {
        float f = W[(size_t)(t * 16 + lh * 8 + j) * N + c * 32 + l31];
        unsigned short h = f2bf(f);
        hv[j] = (short)h;
        lv[j] = (short)f2bf(f - bf2f(h));
    }
    *(short8*)(ph + (size_t)(blockIdx.x * 64 + l) * 8) = hv;
    *(short8*)(pl + (size_t)(blockIdx.x * 64 + l) * 8) = lv;
}

// ---------------- fused sim + top-8: round-13 = shared staging + 16 waves/CU ----------------
// grid 512 (2 blocks/CU), block 512 = 8 waves (2 rowsets rw x 4 colsets cw) -> 4 waves/SIMD.
// Block = 64 rows x 2048 cols (col-half ch). The rw pair of a colset SHARES staged chunks
// (each wave stages half; per-wave counted vmcnt + one raw s_barrier per step joins the pair)
// -> per-CU DMA traffic halves (8->4 MB) and occupancy doubles vs round 12.
// Chunk = 32 cols x 64k x one plane (4KB), 4 bufs/colset, prefetch depth 3.
// Per-(row,ch) top-8 lists written out; exact lexicographic merge happens in gemm_agg.
__global__ __launch_bounds__(512, 4)
void sim_topk_kernel(const unsigned short* __restrict__ khi,
                     const unsigned short* __restrict__ klo,
                     float* __restrict__ svals, int* __restrict__ sidx) {
    __shared__ __align__(16) char smem[4 * 4 * 4096];   // 4 colsets x 4 bufs x 4KB

    const int id = blockIdx.x;
    const int xcd = id & 7;
    const int b = xcd >> 1;                        // batch -> XCD pair (L2 residency)
    const int j = ((id >> 3) << 1) | (xcd & 1);    // 0..127
    const int rowgroup = j >> 1;                   // 0..63
    const int ch = j & 1;                          // col half
    const int rowbase = rowgroup * 64;
    const int colbase = ch * 2048;
    const unsigned short* khiB = khi + (size_t)b * NN * HDIM;
    const unsigned short* kloB = klo + (size_t)b * NN * HDIM;

    const int tid = threadIdx.x;
    const int lane = tid & 63, w = tid >> 6;       // 8 waves
    const int l31 = lane & 31, lh = lane >> 5;
    const int rw = w & 1, cw = w >> 1;             // rowset, colset

    // ---- A: this wave's 32 rows (hi+lo), full K=256, in regs ----
    short8 ah[16], al[16];
    {
        const unsigned short* ph = khiB + (size_t)(rowbase + rw * 32 + l31) * HDIM + lh * 8;
        const unsigned short* pl = kloB + (size_t)(rowbase + rw * 32 + l31) * HDIM + lh * 8;
#pragma unroll
        for (int T = 0; T < 16; ++T) {
            ah[T] = *(const short8*)(ph + T * 16);
            al[T] = *(const short8*)(pl + T * 16);
        }
    }
#pragma unroll
    for (int T = 0; T < 16; ++T) {
        asm volatile("" : "+v"(ah[T]));
        asm volatile("" : "+v"(al[T]));
    }

    char* gbuf = smem + cw * 16384;                // colset-shared 4 x 4KB

    // stage chunk s (cs2=s>>3, sub=s&7: plane=sub&1, kb2=sub>>1): 32 cols x 64k x 1 plane.
    // Each rw wave stages 2 of the 4 x 1KB instrs (full-line: 8 cols x 128B contiguous).
    // Source seg pre-swizzled sg8^sc8 (involution); LDS dest linear lane*16.
    const int sc8 = lane >> 3, sg8 = lane & 7;
    auto stage = [&](int s) {
        const int cs2 = s >> 3, sub = s & 7;
        const int kb2 = sub >> 1;
        const unsigned short* pb = (sub & 1) ? kloB : khiB;
        char* dst = gbuf + (s & 3) * 4096;
        const int c0 = colbase + cw * 512 + cs2 * 32;
#pragma unroll
        for (int ii = 0; ii < 2; ++ii) {
            const int i = rw * 2 + ii;
            const unsigned short* src =
                pb + (size_t)(c0 + i * 8 + sc8) * HDIM + kb2 * 64 + ((sg8 ^ sc8) * 8);
            __builtin_amdgcn_global_load_lds(
                (const __attribute__((address_space(1))) void*)src,
                (__attribute__((address_space(3))) void*)(dst + i * 1024), 16, 0, 0);
        }
    };

    stage(0);
    stage(1);
    stage(2);

    const int key = l31 & 7;
    const int rbase = l31 * 128;
    const int sl0 = ((0 * 2 + lh) ^ key) * 16;
    const int sl1 = ((1 * 2 + lh) ^ key) * 16;
    const int sl2 = ((2 * 2 + lh) ^ key) * 16;
    const int sl3 = ((3 * 2 + lh) ^ key) * 16;

    float tv[8]; int ti[8];
#pragma unroll
    for (int s = 0; s < 8; ++s) { tv[s] = -1e30f; ti[s] = 0x7fffffff; }

    for (int cs = 0; cs < 16; ++cs) {
        f32x16 acc;
#pragma unroll
        for (int r = 0; r < 16; ++r) acc[r] = 0.f;

#pragma unroll
        for (int sub = 0; sub < 8; ++sub) {
            const int s = cs * 8 + sub;
            // own half of chunk s landed (2 loads/step, depth-3: 6 outstanding max)
            if (s < 126)       asm volatile("s_waitcnt vmcnt(4)" ::: "memory");
            else if (s == 126) asm volatile("s_waitcnt vmcnt(2)" ::: "memory");
            else               asm volatile("s_waitcnt vmcnt(0)" ::: "memory");
            __builtin_amdgcn_s_barrier();          // partner's half landed too
            __builtin_amdgcn_sched_barrier(0);

            const char* bufc = gbuf + (s & 3) * 4096;
            short8 B0 = *(const short8*)(bufc + rbase + sl0);
            short8 B1 = *(const short8*)(bufc + rbase + sl1);
            short8 B2 = *(const short8*)(bufc + rbase + sl2);
            short8 B3 = *(const short8*)(bufc + rbase + sl3);
            // buf (s+3)&3 was last read at step s-1, complete before this barrier -> safe
            if (s + 3 < 128) stage(s + 3);

            const int T0 = (sub >> 1) * 4;
            if ((sub & 1) == 0) {   // hi plane: Bh*ah + Bh*al
                acc = MFMA32(B0, ah[T0],     acc);
                acc = MFMA32(B0, al[T0],     acc);
                acc = MFMA32(B1, ah[T0 + 1], acc);
                acc = MFMA32(B1, al[T0 + 1], acc);
                acc = MFMA32(B2, ah[T0 + 2], acc);
                acc = MFMA32(B2, al[T0 + 2], acc);
                acc = MFMA32(B3, ah[T0 + 3], acc);
                acc = MFMA32(B3, al[T0 + 3], acc);
            } else {                // lo plane: Bl*ah
                acc = MFMA32(B0, ah[T0],     acc);
                acc = MFMA32(B1, ah[T0 + 1], acc);
                acc = MFMA32(B2, ah[T0 + 2], acc);
                acc = MFMA32(B3, ah[T0 + 3], acc);
            }
        }

        // scan 16 lane-local sim values (ascending col; strict > = ref tie semantics)
        const int cbase = colbase + cw * 512 + cs * 32 + 4 * lh;
#pragma unroll
        for (int r = 0; r < 16; ++r) {
            float v = acc[r];
            int col = cbase + (r & 3) + 8 * (r >> 2);
            if (v > tv[7]) {
                tv[7] = v; ti[7] = col;
#pragma unroll
                for (int q = 7; q >= 1; --q) {
                    if (tv[q] > tv[q - 1]) {
                        float a0 = tv[q]; tv[q] = tv[q - 1]; tv[q - 1] = a0;
                        int   c0_ = ti[q]; ti[q] = ti[q - 1]; ti[q - 1] = c0_;
                    }
                }
            }
        }
    }

    // ---- merge 8 partial lists per row (4 cw x 2 lh), rows 0..63, lexicographic ----
    __syncthreads();
    float* vbuf = (float*)smem;               // [64][66]
    int*   ibuf = (int*)(smem + 64 * 66 * 4);
    const int list = cw * 2 + lh;
    const int mrow = rw * 32 + l31;
#pragma unroll
    for (int s = 0; s < 8; ++s) {
        vbuf[mrow * 66 + list * 8 + s] = tv[s];
        ibuf[mrow * 66 + list * 8 + s] = ti[s];
    }
    __syncthreads();
    if (tid < 64) {
        float fv[8]; int fi[8];
#pragma unroll
        for (int s = 0; s < 8; ++s) { fv[s] = -1e30f; fi[s] = 0x7fffffff; }
        for (int e = 0; e < 64; ++e) {
            float v = vbuf[tid * 66 + e];
            int  ix = ibuf[tid * 66 + e];
            bool ins = (v > fv[7]) || (v == fv[7] && ix < fi[7]);
            if (ins) {
                fv[7] = v; fi[7] = ix;
#pragma unroll
                for (int q = 7; q >= 1; --q) {
                    bool sw = (fv[q] > fv[q - 1]) || (fv[q] == fv[q - 1] && fi[q] < fi[q - 1]);
                    if (sw) {
                        float a0 = fv[q]; fv[q] = fv[q - 1]; fv[q - 1] = a0;
                        int   c0_ = fi[q]; fi[q] = fi[q - 1]; fi[q - 1] = c0_;
                    }
                }
            }
        }
        const size_t lb = ((size_t)(b * NN + rowbase + tid) * 2 + ch) * 8;
#pragma unroll
        for (int s = 0; s < 8; ++s) { svals[lb + s] = fv[s]; sidx[lb + s] = fi[s]; }
    }
}

// ---------------- MFMA keys GEMM + normalize (unchanged, working) ----------------
__global__ __launch_bounds__(256, 2)
void gemm_keys_mfma(const float* __restrict__ A,
                    const unsigned short* __restrict__ wh, const unsigned short* __restrict__ wl,
                    const float* __restrict__ bias,
                    unsigned short* __restrict__ khi, unsigned short* __restrict__ klo) {
    __shared__ float ssqbuf[2][32][2];
    const int tid = threadIdx.x, lane = tid & 63, w = tid >> 6;
    const int l31 = lane & 31, lh = lane >> 5;
    const int rw = w & 1, cw = w >> 1;
    const int row = blockIdx.x * 64 + rw * 32 + l31;

    short8 ahi[8], alo[8];
    const float* ap = A + (size_t)row * DDIM + lh * 8;
#pragma unroll
    for (int T = 0; T < 8; ++T) {
        float4 f0 = *(const float4*)(ap + T * 16);
        float4 f1 = *(const float4*)(ap + T * 16 + 4);
        float ff[8] = {f0.x, f0.y, f0.z, f0.w, f1.x, f1.y, f1.z, f1.w};
#pragma unroll
        for (int j2 = 0; j2 < 8; ++j2) {
            unsigned short h = f2bf(ff[j2]);
            ahi[T][j2] = (short)h;
            alo[T][j2] = (short)f2bf(ff[j2] - bf2f(h));
        }
    }

    f32x16 acc[4];
#pragma unroll
    for (int ct = 0; ct < 4; ++ct)
#pragma unroll
        for (int r = 0; r < 16; ++r) acc[ct][r] = 0.f;

#pragma unroll
    for (int T = 0; T < 8; ++T) {
#pragma unroll
        for (int ct = 0; ct < 4; ++ct) {
            const size_t pi = (size_t)((T * 8 + cw * 4 + ct) * 64 + lane) * 8;
            short8 bh = *(const short8*)(wh + pi);
            short8 bl = *(const short8*)(wl + pi);
            acc[ct] = MFMA32(bh, ahi[T], acc[ct]);
            acc[ct] = MFMA32(bl, ahi[T], acc[ct]);
            acc[ct] = MFMA32(bh, alo[T], acc[ct]);
        }
    }

    float ss = 0.f;
#pragma unroll
    for (int ct = 0; ct < 4; ++ct)
#pragma unroll
        for (int g = 0; g < 4; ++g) {
            const int c0 = cw * 128 + ct * 32 + g * 8 + lh * 4;
            float4 bz = *(const float4*)(bias + c0);
            float bzf[4] = {bz.x, bz.y, bz.z, bz.w};
#pragma unroll
            for (int j2 = 0; j2 < 4; ++j2) {
                acc[ct][g * 4 + j2] += bzf[j2];
                ss += acc[ct][g * 4 + j2] * acc[ct][g * 4 + j2];
            }
        }
    ss += __shfl_xor(ss, 32);
    if (lh == 0) ssqbuf[rw][l31][cw] = ss;
    __syncthreads();
    float sstot = ssqbuf[rw][l31][0] + ssqbuf[rw][l31][1];
    float scn = 1.0f / fmaxf(sqrtf(sstot), 1e-12f);

#pragma unroll
    for (int ct = 0; ct < 4; ++ct)
#pragma unroll
        for (int g = 0; g < 4; ++g) {
            const int c0 = cw * 128 + ct * 32 + g * 8 + lh * 4;
            short4v hv, lv;
#pragma unroll
            for (int j2 = 0; j2 < 4; ++j2) {
                float vn = acc[ct][g * 4 + j2] * scn;
                unsigned short h = f2bf(vn);
                hv[j2] = (short)h;
                lv[j2] = (short)f2bf(vn - bf2f(h));
            }
            *(short4v*)(khi + (size_t)row * HDIM + c0) = hv;
            *(short4v*)(klo + (size_t)row * HDIM + c0) = lv;
        }
}

// ---------------- MFMA agg GEMM + fused gather/mean + 2-list exact merge ----------------
// Merges the two per-ch sorted top-8 lists via rank computation (static indices; dynamic
// rank-indexed store goes to a private LDS slot -- no scratch). Comparator matches reference
// tie-break (ties -> lower index). Sum order = merged (descending) order, same as before.
__global__ __launch_bounds__(256, 2)
void gemm_agg_mfma(const float* __restrict__ state,
                   const float* __restrict__ svals, const int* __restrict__ sidx,
                   const unsigned short* __restrict__ wh, const unsigned short* __restrict__ wl,
                   const float* __restrict__ bias,
                   unsigned short* __restrict__ oh, unsigned short* __restrict__ ol) {
    __shared__ int mslot[256][8];
    const int tid = threadIdx.x, lane = tid & 63, w = tid >> 6;
    const int l31 = lane & 31, lh = lane >> 5;
    const int rw = w & 1, cw = w >> 1;
    const int row = blockIdx.x * 64 + rw * 32 + l31;
    const int bb = row >> 12;
    const float* sb = state + (size_t)bb * NN * DDIM;

    // ---- merge the two ch lists (each sorted desc, lexicographic) ----
    int ridx[8];
    {
        const size_t lb = (size_t)row * 16;
        float av[8], bv[8]; int ai[8], bi2[8];
#pragma unroll
        for (int k = 0; k < 8; ++k) {
            av[k] = svals[lb + k];     ai[k]  = sidx[lb + k];
            bv[k] = svals[lb + 8 + k]; bi2[k] = sidx[lb + 8 + k];
        }
        int* ms = mslot[tid];
#pragma unroll
        for (int i2 = 0; i2 < 8; ++i2) {
            int r = i2;
#pragma unroll
            for (int j2 = 0; j2 < 8; ++j2)
                r += ((bv[j2] > av[i2]) || (bv[j2] == av[i2] && bi2[j2] < ai[i2])) ? 1 : 0;
            if (r < 8) ms[r] = ai[i2];
        }
#pragma unroll
        for (int j2 = 0; j2 < 8; ++j2) {
            int r = j2;
#pragma unroll
            for (int i2 = 0; i2 < 8; ++i2)
                r += ((av[i2] > bv[j2]) || (av[i2] == bv[j2] && ai[i2] < bi2[j2])) ? 1 : 0;
            if (r < 8) ms[r] = bi2[j2];
        }
#pragma unroll
        for (int k = 0; k < 8; ++k) ridx[k] = ms[k];
    }

    short8 ahi[8], alo[8];
#pragma unroll
    for (int T = 0; T < 8; ++T) {
        float fr[8] = {0.f, 0.f, 0.f, 0.f, 0.f, 0.f, 0.f, 0.f};
#pragma unroll
        for (int k = 0; k < 8; ++k) {
            const float* rp = sb + (size_t)ridx[k] * DDIM + T * 16 + lh * 8;
            float4 f0 = *(const float4*)rp;
            float4 f1 = *(const float4*)(rp + 4);
            fr[0] += f0.x; fr[1] += f0.y; fr[2] += f0.z; fr[3] += f0.w;
            fr[4] += f1.x; fr[5] += f1.y; fr[6] += f1.z; fr[7] += f1.w;
        }
#pragma unroll
        for (int j2 = 0; j2 < 8; ++j2) {
            float v = fr[j2] * 0.125f;
            unsigned short h = f2bf(v);
            ahi[T][j2] = (short)h;
            alo[T][j2] = (short)f2bf(v - bf2f(h));
        }
    }

    f32x16 acc[4];
#pragma unroll
    for (int ct = 0; ct < 4; ++ct)
#pragma unroll
        for (int r = 0; r < 16; ++r) acc[ct][r] = 0.f;

#pragma unroll
    for (int T = 0; T < 8; ++T) {
#pragma unroll
        for (int ct = 0; ct < 4; ++ct) {
            const size_t pi = (size_t)((T * 8 + cw * 4 + ct) * 64 + lane) * 8;
            short8 bh = *(const short8*)(wh + pi);
            short8 bl = *(const short8*)(wl + pi);
            acc[ct] = MFMA32(bh, ahi[T], acc[ct]);
            acc[ct] = MFMA32(bl, ahi[T], acc[ct]);
            acc[ct] = MFMA32(bh, alo[T], acc[ct]);
        }
    }

#pragma unroll
    for (int ct = 0; ct < 4; ++ct)
#pragma unroll
        for (int g = 0; g < 4; ++g) {
            const int c0 = cw * 128 + ct * 32 + g * 8 + lh * 4;
            float4 bz = *(const float4*)(bias + c0);
            float bzf[4] = {bz.x, bz.y, bz.z, bz.w};
            short4v hv, lv;
#pragma unroll
            for (int j2 = 0; j2 < 4; ++j2) {
                float vn = acc[ct][g * 4 + j2] + bzf[j2];
                unsigned short h = f2bf(vn);
                hv[j2] = (short)h;
                lv[j2] = (short)f2bf(vn - bf2f(h));
            }
            *(short4v*)(oh + (size_t)row * HDIM + c0) = hv;
            *(short4v*)(ol + (size_t)row * HDIM + c0) = lv;
        }
}

// ---------------- MFMA concat GEMM (K=384) + LN + silu (unchanged) ----------------
__global__ __launch_bounds__(256, 2)
void gemm_ln_mfma(const float* __restrict__ state,
                  const unsigned short* __restrict__ agh, const unsigned short* __restrict__ agl,
                  const unsigned short* __restrict__ wh, const unsigned short* __restrict__ wl,
                  const float* __restrict__ b1, const float* __restrict__ lng,
                  const float* __restrict__ lnb,
                  unsigned short* __restrict__ gh, unsigned short* __restrict__ gl) {
    __shared__ float s1buf[2][32][2], s2buf[2][32][2];
    const int tid = threadIdx.x, lane = tid & 63, w = tid >> 6;
    const int l31 = lane & 31, lh = lane >> 5;
    const int rw = w & 1, cw = w >> 1;
    const int row = blockIdx.x * 64 + rw * 32 + l31;

    f32x16 acc[4];
#pragma unroll
    for (int ct = 0; ct < 4; ++ct)
#pragma unroll
        for (int r = 0; r < 16; ++r) acc[ct][r] = 0.f;

    short8 ahi[8], alo[8];
    {
        const float* ap = state + (size_t)row * DDIM + lh * 8;
#pragma unroll
        for (int T = 0; T < 8; ++T) {
            float4 f0 = *(const float4*)(ap + T * 16);
            float4 f1 = *(const float4*)(ap + T * 16 + 4);
            float ff[8] = {f0.x, f0.y, f0.z, f0.w, f1.x, f1.y, f1.z, f1.w};
#pragma unroll
            for (int j2 = 0; j2 < 8; ++j2) {
                unsigned short h = f2bf(ff[j2]);
                ahi[T][j2] = (short)h;
                alo[T][j2] = (short)f2bf(ff[j2] - bf2f(h));
            }
        }
#pragma unroll
        for (int T = 0; T < 8; ++T)
#pragma unroll
            for (int ct = 0; ct < 4; ++ct) {
                const size_t pi = (size_t)((T * 8 + cw * 4 + ct) * 64 + lane) * 8;
                short8 bh = *(const short8*)(wh + pi);
                short8 bl = *(const short8*)(wl + pi);
                acc[ct] = MFMA32(bh, ahi[T], acc[ct]);
                acc[ct] = MFMA32(bl, ahi[T], acc[ct]);
                acc[ct] = MFMA32(bh, alo[T], acc[ct]);
            }
    }
#pragma unroll
    for (int kc = 1; kc < 3; ++kc) {
#pragma unroll
        for (int T = 0; T < 8; ++T) {
            ahi[T] = *(const short8*)(agh + (size_t)row * HDIM + (kc - 1) * 128 + T * 16 + lh * 8);
            alo[T] = *(const short8*)(agl + (size_t)row * HDIM + (kc - 1) * 128 + T * 16 + lh * 8);
        }
#pragma unroll
        for (int T = 0; T < 8; ++T)
#pragma unroll
            for (int ct = 0; ct < 4; ++ct) {
                const size_t pi = (size_t)(((kc * 8 + T) * 8 + cw * 4 + ct) * 64 + lane) * 8;
                short8 bh = *(const short8*)(wh + pi);
                short8 bl = *(const short8*)(wl + pi);
                acc[ct] = MFMA32(bh, ahi[T], acc[ct]);
                acc[ct] = MFMA32(bl, ahi[T], acc[ct]);
                acc[ct] = MFMA32(bh, alo[T], acc[ct]);
            }
    }

    float s1 = 0.f, s2 = 0.f;
#pragma unroll
    for (int ct = 0; ct < 4; ++ct)
#pragma unroll
        for (int g = 0; g < 4; ++g) {
            const int c0 = cw * 128 + ct * 32 + g * 8 + lh * 4;
            float4 bz = *(const float4*)(b1 + c0);
            float bzf[4] = {bz.x, bz.y, bz.z, bz.w};
#pragma unroll
            for (int j2 = 0; j2 < 4; ++j2) {
                acc[ct][g * 4 + j2] += bzf[j2];
                s1 += acc[ct][g * 4 + j2];
                s2 += acc[ct][g * 4 + j2] * acc[ct][g * 4 + j2];
            }
        }
    s1 += __shfl_xor(s1, 32);
    s2 += __shfl_xor(s2, 32);
    if (lh == 0) { s1buf[rw][l31][cw] = s1; s2buf[rw][l31][cw] = s2; }
    __syncthreads();
    float s1t = s1buf[rw][l31][0] + s1buf[rw][l31][1];
    float s2t = s2buf[rw][l31][0] + s2buf[rw][l31][1];
    float mu = s1t * (1.0f / HDIM);
    float var = s2t * (1.0f / HDIM) - mu * mu;
    float inv = 1.0f / sqrtf(var + 1e-5f);

#pragma unroll
    for (int ct = 0; ct < 4; ++ct)
#pragma unroll
        for (int g = 0; g < 4; ++g) {
            const int c0 = cw * 128 + ct * 32 + g * 8 + lh * 4;
            float4 gg = *(const float4*)(lng + c0);
            float4 bb = *(const float4*)(lnb + c0);
            float ggf[4] = {gg.x, gg.y, gg.z, gg.w};
            float bbf[4] = {bb.x, bb.y, bb.z, bb.w};
            short4v hv, lv;
#pragma unroll
            for (int j2 = 0; j2 < 4; ++j2) {
                float hval = (acc[ct][g * 4 + j2] - mu) * inv * ggf[j2] + bbf[j2];
                float gval = hval / (1.0f + expf(-hval));
                unsigned short h = f2bf(gval);
                hv[j2] = (short)h;
                lv[j2] = (short)f2bf(gval - bf2f(h));
            }
            *(short4v*)(gh + (size_t)row * HDIM + c0) = hv;
            *(short4v*)(gl + (size_t)row * HDIM + c0) = lv;
        }
}

// ---------------- MFMA update GEMM (unchanged) ----------------
__global__ __launch_bounds__(256, 2)
void gemm_upd_mfma(const unsigned short* __restrict__ gh, const unsigned short* __restrict__ gl,
                   const unsigned short* __restrict__ wh, const unsigned short* __restrict__ wl,
                   const float* __restrict__ b2, float* __restrict__ state) {
    const int tid = threadIdx.x, lane = tid & 63, w = tid >> 6;
    const int l31 = lane & 31, lh = lane >> 5;
    const int rw = w & 1, cw = w >> 1;
    const int row = blockIdx.x * 64 + rw * 32 + l31;

    f32x16 acc[2];
#pragma unroll
    for (int ct = 0; ct < 2; ++ct)
#pragma unroll
        for (int r = 0; r < 16; ++r) acc[ct][r] = 0.f;

    short8 ahi[8], alo[8];
#pragma unroll
    for (int kc = 0; kc < 2; ++kc) {
#pragma unroll
        for (int T = 0; T < 8; ++T) {
            ahi[T] = *(const short8*)(gh + (size_t)row * HDIM + kc * 128 + T * 16 + lh * 8);
            alo[T] = *(const short8*)(gl + (size_t)row * HDIM + kc * 128 + T * 16 + lh * 8);
        }
#pragma unroll
        for (int T = 0; T < 8; ++T)
#pragma unroll
            for (int ct = 0; ct < 2; ++ct) {
                const size_t pi = (size_t)(((kc * 8 + T) * 4 + cw * 2 + ct) * 64 + lane) * 8;
                short8 bh = *(const short8*)(wh + pi);
                short8 bl = *(const short8*)(wl + pi);
                acc[ct] = MFMA32(bh, ahi[T], acc[ct]);
                acc[ct] = MFMA32(bl, ahi[T], acc[ct]);
                acc[ct] = MFMA32(bh, alo[T], acc[ct]);
            }
    }

#pragma unroll
    for (int ct = 0; ct < 2; ++ct)
#pragma unroll
        for (int g = 0; g < 4; ++g) {
            const int c0 = cw * 64 + ct * 32 + g * 8 + lh * 4;
            float4 bz = *(const float4*)(b2 + c0);
            float bzf[4] = {bz.x, bz.y, bz.z, bz.w};
            float4* sp = (float4*)(state + (size_t)row * DDIM + c0);
            float4 sv = *sp;
            float svf[4] = {sv.x, sv.y, sv.z, sv.w};
#pragma unroll
            for (int j2 = 0; j2 < 4; ++j2) svf[j2] += acc[ct][g * 4 + j2] + bzf[j2];
            sv.x = svf[0]; sv.y = svf[1]; sv.z = svf[2]; sv.w = svf[3];
            *sp = sv;
        }
}

// ---------------- final reduction (unchanged) ----------------
__global__ void partial_mean_kernel(const float* __restrict__ state, float* __restrict__ partial) {
    int b = blockIdx.y, seg = blockIdx.x, tid = threadIdx.x;
    const float* sp = state + ((size_t)b * NN + (size_t)seg * 128) * DDIM;
    float acc = 0.f;
    for (int i = 0; i < 128; ++i) acc += sp[(size_t)i * DDIM + tid];
    partial[((size_t)b * 32 + seg) * DDIM + tid] = acc;
}

__global__ void final_out_kernel(const float* __restrict__ partial, const float* __restrict__ Wo,
                                 const float* __restrict__ bo, float* __restrict__ out) {
    __shared__ float mean[BQ][DDIM];
    int tid = threadIdx.x;
    for (int o = tid; o < BQ * DDIM; o += 256) {
        int b = o >> 7, d = o & 127;
        float s = 0.f;
        for (int p = 0; p < 32; ++p) s += partial[((size_t)b * 32 + p) * DDIM + d];
        mean[b][d] = s * (1.0f / NN);
    }
    __syncthreads();
    for (int o = tid; o < BQ * DDIM; o += 256) {
        int b = o >> 7, c = o & 127;
        float acc = bo[c];
        for (int d = 0; d < DDIM; ++d) acc += mean[b][d] * Wo[d * DDIM + c];
        out[o] = acc;
    }
}

extern "C" void kernel_launch(void* const* d_in, const int* in_sizes, int n_in,
                              void* d_out, int out_size, void* d_ws, size_t ws_size,
                              hipStream_t stream) {
    const float* x   = (const float*)d_in[0];
    const float* Wn  = (const float*)d_in[1];
    const float* bn  = (const float*)d_in[2];
    const float* W1  = (const float*)d_in[3];
    const float* b1  = (const float*)d_in[4];
    const float* lng = (const float*)d_in[5];
    const float* lnb = (const float*)d_in[6];
    const float* W2  = (const float*)d_in[7];
    const float* b2  = (const float*)d_in[8];
    const float* Wo  = (const float*)d_in[9];
    const float* bo  = (const float*)d_in[10];
    float* out = (float*)d_out;

    float* ws    = (float*)d_ws;
    float* state = ws;
    unsigned short* agghi = (unsigned short*)(state + (size_t)RTOT * DDIM);
    unsigned short* agglo = agghi + (size_t)RTOT * HDIM;
    unsigned short* khi_b = agglo + (size_t)RTOT * HDIM;
    unsigned short* klo_b = khi_b + (size_t)RTOT * HDIM;
    unsigned short* ghi = khi_b;                               // alias (khi dead after sim)
    unsigned short* glo = klo_b;                               // alias (klo dead after sim)
    float* partial = (float*)(klo_b + (size_t)RTOT * HDIM);
    float* svals   = partial + (size_t)BQ * 32 * DDIM;         // RTOT*16 f32
    int*   sidx    = (int*)(svals + (size_t)RTOT * 16);        // RTOT*16 i32
    unsigned short* wnh = (unsigned short*)(sidx + (size_t)RTOT * 16);
    unsigned short* wnl = wnh + 128 * 256;
    unsigned short* w1h = wnl + 128 * 256;
    unsigned short* w1l = w1h + 384 * 256;
    unsigned short* w2h = w1l + 384 * 256;
    unsigned short* w2l = w2h + 256 * 128;

    hipMemcpyAsync(state, x, (size_t)RTOT * DDIM * sizeof(float),
                   hipMemcpyDeviceToDevice, stream);

    pack_w_kernel<<<(128 / 16) * (256 / 32), 64, 0, stream>>>(Wn, 256, wnh, wnl);
    pack_w_kernel<<<(384 / 16) * (256 / 32), 64, 0, stream>>>(W1, 256, w1h, w1l);
    pack_w_kernel<<<(256 / 16) * (128 / 32), 64, 0, stream>>>(W2, 128, w2h, w2l);

    for (int step = 0; step < 3; ++step) {
        gemm_keys_mfma<<<RTOT / 64, 256, 0, stream>>>(state, wnh, wnl, bn, khi_b, klo_b);
        sim_topk_kernel<<<512, 512, 0, stream>>>(khi_b, klo_b, svals, sidx);
        gemm_agg_mfma<<<RTOT / 64, 256, 0, stream>>>(state, svals, sidx, wnh, wnl, bn,
                                                     agghi, agglo);
        gemm_ln_mfma<<<RTOT / 64, 256, 0, stream>>>(state, agghi, agglo, w1h, w1l,
                                                    b1, lng, lnb, ghi, glo);
        gemm_upd_mfma<<<RTOT / 64, 256, 0, stream>>>(ghi, glo, w2h, w2l, b2, state);
    }
    partial_mean_kernel<<<dim3(32, BQ), 128, 0, stream>>>(state, partial);
    final_out_kernel<<<1, 256, 0, stream>>>(partial, Wo, bo, out);
}

// Round 14
// 1034.858 us; speedup vs baseline: 1.2769x; 1.2769x over previous
//
#include <hip/hip_runtime.h>

#define DDIM 128
#define HDIM 256
#define BQ   4
#define NN   4096
#define RTOT (BQ*NN)

typedef short short8 __attribute__((ext_vector_type(8)));
typedef short short4v __attribute__((ext_vector_type(4)));
typedef float f32x16 __attribute__((ext_vector_type(16)));

__device__ inline unsigned short f2bf(float f) {
    unsigned int u = __float_as_uint(f);
    unsigned int r = (u + 0x7fffu + ((u >> 16) & 1u)) >> 16;
    return (unsigned short)r;
}
__device__ inline float bf2f(unsigned short h) {
    return __uint_as_float(((unsigned int)h) << 16);
}

#define MFMA32(a, b, c) __builtin_amdgcn_mfma_f32_32x32x16_bf16(a, b, c, 0, 0, 0)

// ---------------- weight packer (unchanged) ----------------
__global__ void pack_w_kernel(const float* __restrict__ W, int N,
                              unsigned short* __restrict__ ph, unsigned short* __restrict__ pl) {
    int l = threadIdx.x, l31 = l & 31, lh = l >> 5;
    int nt = N >> 5;
    int t = blockIdx.x / nt, c = blockIdx.x % nt;
    short8 hv, lv;
#pragma unroll
    for (int j = 0; j < 8; ++j) {
        float f = W[(size_t)(t * 16 + lh * 8 + j) * N + c * 32 + l31];
        unsigned short h = f2bf(f);
        hv[j] = (short)h;
        lv[j] = (short)f2bf(f - bf2f(h));
    }
    *(short8*)(ph + (size_t)(blockIdx.x * 64 + l) * 8) = hv;
    *(short8*)(pl + (size_t)(blockIdx.x * 64 + l) * 8) = lv;
}

// ---------------- fused sim + top-8: round-14 = round-9 protocol, 3 blocks/CU ----------------
// grid 1024 (col-half split ch), block 256 = 4 waves, launch_bounds(256,2) (VGPR cap 256 --
// NO spill; round-13's (512,4) capped at 128 and spilled A). LDS = 3 bufs x 4KB x 4 waves
// = 48 KB -> 3 blocks/CU resident (round 9-12 were LDS-capped at 2 with 64KB + grid 512).
// Block = 32 rows x 2048 cols; wave = 32 rows x 512 cols, 128 steps. Protocol byte-identical
// to round 9 (vmcnt(4)/lgkmcnt(4), reads-before-stage, conflict-free key (l31>>1)&3).
// Per-(row,ch) top-8 lists out; exact lexicographic merge + gather fused in gemm_agg.
__global__ __launch_bounds__(256, 2)
void sim_topk_kernel(const unsigned short* __restrict__ khi,
                     const unsigned short* __restrict__ klo,
                     float* __restrict__ svals, int* __restrict__ sidx) {
    __shared__ __align__(16) char smem[4 * 3 * 4096];   // 4 waves x 3 bufs x 4KB = 48 KB

    const int id = blockIdx.x;
    const int xcd = id & 7;
    const int b = xcd >> 1;                        // batch -> XCD pair (L2 residency)
    const int j = ((id >> 3) << 1) | (xcd & 1);    // 0..255
    const int rowgroup = j >> 1;                   // 0..127
    const int ch = j & 1;                          // col half
    const int rowbase = rowgroup * 32;
    const int colbase = ch * 2048;
    const unsigned short* khiB = khi + (size_t)b * NN * HDIM;
    const unsigned short* kloB = klo + (size_t)b * NN * HDIM;

    const int tid = threadIdx.x;
    const int lane = tid & 63, w = tid >> 6;
    const int l31 = lane & 31, lh = lane >> 5;

    // ---- A: 32 rows (hi+lo), full K=256, in regs (MFMA B-operand) ----
    short8 ah[16], al[16];
    {
        const unsigned short* ph = khiB + (size_t)(rowbase + l31) * HDIM + lh * 8;
        const unsigned short* pl = kloB + (size_t)(rowbase + l31) * HDIM + lh * 8;
#pragma unroll
        for (int T = 0; T < 16; ++T) {
            ah[T] = *(const short8*)(ph + T * 16);
            al[T] = *(const short8*)(pl + T * 16);
        }
    }
#pragma unroll
    for (int T = 0; T < 16; ++T) {
        asm volatile("" : "+v"(ah[T]));
        asm volatile("" : "+v"(al[T]));
    }

    char* mybuf = smem + w * 12288;               // wave-private 3 x 4KB

    // chunk s = (cs, ks): cols [colbase + w*512 + cs*32, +32), K [ks*32, +32), hi+lo.
    const int sc = lane >> 2, sg = lane & 3;
    const int ssw = (sg ^ ((sc >> 1) & 3)) * 8;
    auto stage = [&](int s) {
        const int cs2 = s >> 3, ks2 = s & 7;
        char* dst = mybuf + (s % 3) * 4096;
        const int c0 = colbase + w * 512 + cs2 * 32;
#pragma unroll
        for (int p = 0; p < 2; ++p) {
            const unsigned short* pb = p ? kloB : khiB;
#pragma unroll
            for (int i = 0; i < 2; ++i) {
                const unsigned short* src = pb + (size_t)(c0 + i * 16 + sc) * HDIM + ks2 * 32 + ssw;
                __builtin_amdgcn_global_load_lds(
                    (const __attribute__((address_space(1))) void*)src,
                    (__attribute__((address_space(3))) void*)(dst + p * 2048 + i * 1024), 16, 0, 0);
            }
        }
    };

    stage(0);
    stage(1);

    const int key = (l31 >> 1) & 3;
    const int rb0 = l31 * 64 + ((lh ^ key) * 16);
    const int rb1 = l31 * 64 + (((2 + lh) ^ key) * 16);

    float tv[8]; int ti[8];
#pragma unroll
    for (int s = 0; s < 8; ++s) { tv[s] = -1e30f; ti[s] = 0x7fffffff; }

    for (int cs = 0; cs < 16; ++cs) {
        f32x16 acc;
#pragma unroll
        for (int r = 0; r < 16; ++r) acc[r] = 0.f;

#pragma unroll
        for (int ks = 0; ks < 8; ++ks) {
            const int s = cs * 8 + ks;
            if (s < 127) asm volatile("s_waitcnt vmcnt(4)" ::: "memory");
            else         asm volatile("s_waitcnt vmcnt(0)" ::: "memory");

            const char* bufc = mybuf + (s % 3) * 4096;
            short8 Bh0 = *(const short8*)(bufc + rb0);
            short8 Bl0 = *(const short8*)(bufc + 2048 + rb0);
            short8 Bh1 = *(const short8*)(bufc + rb1);
            short8 Bl1 = *(const short8*)(bufc + 2048 + rb1);
            asm volatile("s_waitcnt lgkmcnt(4)" ::: "memory");
            if (s + 2 < 128) stage(s + 2);

            const int T0 = ks * 2, T1 = ks * 2 + 1;
            acc = MFMA32(Bh0, ah[T0], acc);
            acc = MFMA32(Bh0, al[T0], acc);
            acc = MFMA32(Bl0, ah[T0], acc);
            acc = MFMA32(Bh1, ah[T1], acc);
            acc = MFMA32(Bh1, al[T1], acc);
            acc = MFMA32(Bl1, ah[T1], acc);
        }

        // scan 16 lane-local sim values (ascending col; strict > = ref tie semantics)
        const int cbase = colbase + w * 512 + cs * 32 + 4 * lh;
#pragma unroll
        for (int r = 0; r < 16; ++r) {
            float v = acc[r];
            int col = cbase + (r & 3) + 8 * (r >> 2);
            if (v > tv[7]) {
                tv[7] = v; ti[7] = col;
#pragma unroll
                for (int q = 7; q >= 1; --q) {
                    if (tv[q] > tv[q - 1]) {
                        float a0 = tv[q]; tv[q] = tv[q - 1]; tv[q - 1] = a0;
                        int   c0_ = ti[q]; ti[q] = ti[q - 1]; ti[q - 1] = c0_;
                    }
                }
            }
        }
    }

    // ---- merge 8 partial lists per row (4 waves x 2 lh) -> per-(row,ch) top-8 ----
    __syncthreads();
    float* vbuf = (float*)smem;               // [32][66]
    int*   ibuf = (int*)(smem + 32 * 66 * 4);
    const int list = w * 2 + lh;
#pragma unroll
    for (int s = 0; s < 8; ++s) {
        vbuf[l31 * 66 + list * 8 + s] = tv[s];
        ibuf[l31 * 66 + list * 8 + s] = ti[s];
    }
    __syncthreads();
    if (tid < 32) {
        float fv[8]; int fi[8];
#pragma unroll
        for (int s = 0; s < 8; ++s) { fv[s] = -1e30f; fi[s] = 0x7fffffff; }
        for (int e = 0; e < 64; ++e) {
            float v = vbuf[tid * 66 + e];
            int  ix = ibuf[tid * 66 + e];
            bool ins = (v > fv[7]) || (v == fv[7] && ix < fi[7]);
            if (ins) {
                fv[7] = v; fi[7] = ix;
#pragma unroll
                for (int q = 7; q >= 1; --q) {
                    bool sw = (fv[q] > fv[q - 1]) || (fv[q] == fv[q - 1] && fi[q] < fi[q - 1]);
                    if (sw) {
                        float a0 = fv[q]; fv[q] = fv[q - 1]; fv[q - 1] = a0;
                        int   c0_ = fi[q]; fi[q] = fi[q - 1]; fi[q - 1] = c0_;
                    }
                }
            }
        }
        const size_t lb = ((size_t)(b * NN + rowbase + tid) * 2 + ch) * 8;
#pragma unroll
        for (int s = 0; s < 8; ++s) { svals[lb + s] = fv[s]; sidx[lb + s] = fi[s]; }
    }
}

// ---------------- MFMA keys GEMM + normalize (unchanged, working) ----------------
__global__ __launch_bounds__(256, 2)
void gemm_keys_mfma(const float* __restrict__ A,
                    const unsigned short* __restrict__ wh, const unsigned short* __restrict__ wl,
                    const float* __restrict__ bias,
                    unsigned short* __restrict__ khi, unsigned short* __restrict__ klo) {
    __shared__ float ssqbuf[2][32][2];
    const int tid = threadIdx.x, lane = tid & 63, w = tid >> 6;
    const int l31 = lane & 31, lh = lane >> 5;
    const int rw = w & 1, cw = w >> 1;
    const int row = blockIdx.x * 64 + rw * 32 + l31;

    short8 ahi[8], alo[8];
    const float* ap = A + (size_t)row * DDIM + lh * 8;
#pragma unroll
    for (int T = 0; T < 8; ++T) {
        float4 f0 = *(const float4*)(ap + T * 16);
        float4 f1 = *(const float4*)(ap + T * 16 + 4);
        float ff[8] = {f0.x, f0.y, f0.z, f0.w, f1.x, f1.y, f1.z, f1.w};
#pragma unroll
        for (int j2 = 0; j2 < 8; ++j2) {
            unsigned short h = f2bf(ff[j2]);
            ahi[T][j2] = (short)h;
            alo[T][j2] = (short)f2bf(ff[j2] - bf2f(h));
        }
    }

    f32x16 acc[4];
#pragma unroll
    for (int ct = 0; ct < 4; ++ct)
#pragma unroll
        for (int r = 0; r < 16; ++r) acc[ct][r] = 0.f;

#pragma unroll
    for (int T = 0; T < 8; ++T) {
#pragma unroll
        for (int ct = 0; ct < 4; ++ct) {
            const size_t pi = (size_t)((T * 8 + cw * 4 + ct) * 64 + lane) * 8;
            short8 bh = *(const short8*)(wh + pi);
            short8 bl = *(const short8*)(wl + pi);
            acc[ct] = MFMA32(bh, ahi[T], acc[ct]);
            acc[ct] = MFMA32(bl, ahi[T], acc[ct]);
            acc[ct] = MFMA32(bh, alo[T], acc[ct]);
        }
    }

    float ss = 0.f;
#pragma unroll
    for (int ct = 0; ct < 4; ++ct)
#pragma unroll
        for (int g = 0; g < 4; ++g) {
            const int c0 = cw * 128 + ct * 32 + g * 8 + lh * 4;
            float4 bz = *(const float4*)(bias + c0);
            float bzf[4] = {bz.x, bz.y, bz.z, bz.w};
#pragma unroll
            for (int j2 = 0; j2 < 4; ++j2) {
                acc[ct][g * 4 + j2] += bzf[j2];
                ss += acc[ct][g * 4 + j2] * acc[ct][g * 4 + j2];
            }
        }
    ss += __shfl_xor(ss, 32);
    if (lh == 0) ssqbuf[rw][l31][cw] = ss;
    __syncthreads();
    float sstot = ssqbuf[rw][l31][0] + ssqbuf[rw][l31][1];
    float scn = 1.0f / fmaxf(sqrtf(sstot), 1e-12f);

#pragma unroll
    for (int ct = 0; ct < 4; ++ct)
#pragma unroll
        for (int g = 0; g < 4; ++g) {
            const int c0 = cw * 128 + ct * 32 + g * 8 + lh * 4;
            short4v hv, lv;
#pragma unroll
            for (int j2 = 0; j2 < 4; ++j2) {
                float vn = acc[ct][g * 4 + j2] * scn;
                unsigned short h = f2bf(vn);
                hv[j2] = (short)h;
                lv[j2] = (short)f2bf(vn - bf2f(h));
            }
            *(short4v*)(khi + (size_t)row * HDIM + c0) = hv;
            *(short4v*)(klo + (size_t)row * HDIM + c0) = lv;
        }
}

// ---------------- MFMA agg GEMM + fused gather/mean + 2-list exact merge (round-13, proven) --
__global__ __launch_bounds__(256, 2)
void gemm_agg_mfma(const float* __restrict__ state,
                   const float* __restrict__ svals, const int* __restrict__ sidx,
                   const unsigned short* __restrict__ wh, const unsigned short* __restrict__ wl,
                   const float* __restrict__ bias,
                   unsigned short* __restrict__ oh, unsigned short* __restrict__ ol) {
    __shared__ int mslot[256][8];
    const int tid = threadIdx.x, lane = tid & 63, w = tid >> 6;
    const int l31 = lane & 31, lh = lane >> 5;
    const int rw = w & 1, cw = w >> 1;
    const int row = blockIdx.x * 64 + rw * 32 + l31;
    const int bb = row >> 12;
    const float* sb = state + (size_t)bb * NN * DDIM;

    int ridx[8];
    {
        const size_t lb = (size_t)row * 16;
        float av[8], bv[8]; int ai[8], bi2[8];
#pragma unroll
        for (int k = 0; k < 8; ++k) {
            av[k] = svals[lb + k];     ai[k]  = sidx[lb + k];
            bv[k] = svals[lb + 8 + k]; bi2[k] = sidx[lb + 8 + k];
        }
        int* ms = mslot[tid];
#pragma unroll
        for (int i2 = 0; i2 < 8; ++i2) {
            int r = i2;
#pragma unroll
            for (int j2 = 0; j2 < 8; ++j2)
                r += ((bv[j2] > av[i2]) || (bv[j2] == av[i2] && bi2[j2] < ai[i2])) ? 1 : 0;
            if (r < 8) ms[r] = ai[i2];
        }
#pragma unroll
        for (int j2 = 0; j2 < 8; ++j2) {
            int r = j2;
#pragma unroll
            for (int i2 = 0; i2 < 8; ++i2)
                r += ((av[i2] > bv[j2]) || (av[i2] == bv[j2] && ai[i2] < bi2[j2])) ? 1 : 0;
            if (r < 8) ms[r] = bi2[j2];
        }
#pragma unroll
        for (int k = 0; k < 8; ++k) ridx[k] = ms[k];
    }

    short8 ahi[8], alo[8];
#pragma unroll
    for (int T = 0; T < 8; ++T) {
        float fr[8] = {0.f, 0.f, 0.f, 0.f, 0.f, 0.f, 0.f, 0.f};
#pragma unroll
        for (int k = 0; k < 8; ++k) {
            const float* rp = sb + (size_t)ridx[k] * DDIM + T * 16 + lh * 8;
            float4 f0 = *(const float4*)rp;
            float4 f1 = *(const float4*)(rp + 4);
            fr[0] += f0.x; fr[1] += f0.y; fr[2] += f0.z; fr[3] += f0.w;
            fr[4] += f1.x; fr[5] += f1.y; fr[6] += f1.z; fr[7] += f1.w;
        }
#pragma unroll
        for (int j2 = 0; j2 < 8; ++j2) {
            float v = fr[j2] * 0.125f;
            unsigned short h = f2bf(v);
            ahi[T][j2] = (short)h;
            alo[T][j2] = (short)f2bf(v - bf2f(h));
        }
    }

    f32x16 acc[4];
#pragma unroll
    for (int ct = 0; ct < 4; ++ct)
#pragma unroll
        for (int r = 0; r < 16; ++r) acc[ct][r] = 0.f;

#pragma unroll
    for (int T = 0; T < 8; ++T) {
#pragma unroll
        for (int ct = 0; ct < 4; ++ct) {
            const size_t pi = (size_t)((T * 8 + cw * 4 + ct) * 64 + lane) * 8;
            short8 bh = *(const short8*)(wh + pi);
            short8 bl = *(const short8*)(wl + pi);
            acc[ct] = MFMA32(bh, ahi[T], acc[ct]);
            acc[ct] = MFMA32(bl, ahi[T], acc[ct]);
            acc[ct] = MFMA32(bh, alo[T], acc[ct]);
        }
    }

#pragma unroll
    for (int ct = 0; ct < 4; ++ct)
#pragma unroll
        for (int g = 0; g < 4; ++g) {
            const int c0 = cw * 128 + ct * 32 + g * 8 + lh * 4;
            float4 bz = *(const float4*)(bias + c0);
            float bzf[4] = {bz.x, bz.y, bz.z, bz.w};
            short4v hv, lv;
#pragma unroll
            for (int j2 = 0; j2 < 4; ++j2) {
                float vn = acc[ct][g * 4 + j2] + bzf[j2];
                unsigned short h = f2bf(vn);
                hv[j2] = (short)h;
                lv[j2] = (short)f2bf(vn - bf2f(h));
            }
            *(short4v*)(oh + (size_t)row * HDIM + c0) = hv;
            *(short4v*)(ol + (size_t)row * HDIM + c0) = lv;
        }
}

// ---------------- MFMA concat GEMM (K=384) + LN + silu (unchanged) ----------------
__global__ __launch_bounds__(256, 2)
void gemm_ln_mfma(const float* __restrict__ state,
                  const unsigned short* __restrict__ agh, const unsigned short* __restrict__ agl,
                  const unsigned short* __restrict__ wh, const unsigned short* __restrict__ wl,
                  const float* __restrict__ b1, const float* __restrict__ lng,
                  const float* __restrict__ lnb,
                  unsigned short* __restrict__ gh, unsigned short* __restrict__ gl) {
    __shared__ float s1buf[2][32][2], s2buf[2][32][2];
    const int tid = threadIdx.x, lane = tid & 63, w = tid >> 6;
    const int l31 = lane & 31, lh = lane >> 5;
    const int rw = w & 1, cw = w >> 1;
    const int row = blockIdx.x * 64 + rw * 32 + l31;

    f32x16 acc[4];
#pragma unroll
    for (int ct = 0; ct < 4; ++ct)
#pragma unroll
        for (int r = 0; r < 16; ++r) acc[ct][r] = 0.f;

    short8 ahi[8], alo[8];
    {
        const float* ap = state + (size_t)row * DDIM + lh * 8;
#pragma unroll
        for (int T = 0; T < 8; ++T) {
            float4 f0 = *(const float4*)(ap + T * 16);
            float4 f1 = *(const float4*)(ap + T * 16 + 4);
            float ff[8] = {f0.x, f0.y, f0.z, f0.w, f1.x, f1.y, f1.z, f1.w};
#pragma unroll
            for (int j2 = 0; j2 < 8; ++j2) {
                unsigned short h = f2bf(ff[j2]);
                ahi[T][j2] = (short)h;
                alo[T][j2] = (short)f2bf(ff[j2] - bf2f(h));
            }
        }
#pragma unroll
        for (int T = 0; T < 8; ++T)
#pragma unroll
            for (int ct = 0; ct < 4; ++ct) {
                const size_t pi = (size_t)((T * 8 + cw * 4 + ct) * 64 + lane) * 8;
                short8 bh = *(const short8*)(wh + pi);
                short8 bl = *(const short8*)(wl + pi);
                acc[ct] = MFMA32(bh, ahi[T], acc[ct]);
                acc[ct] = MFMA32(bl, ahi[T], acc[ct]);
                acc[ct] = MFMA32(bh, alo[T], acc[ct]);
            }
    }
#pragma unroll
    for (int kc = 1; kc < 3; ++kc) {
#pragma unroll
        for (int T = 0; T < 8; ++T) {
            ahi[T] = *(const short8*)(agh + (size_t)row * HDIM + (kc - 1) * 128 + T * 16 + lh * 8);
            alo[T] = *(const short8*)(agl + (size_t)row * HDIM + (kc - 1) * 128 + T * 16 + lh * 8);
        }
#pragma unroll
        for (int T = 0; T < 8; ++T)
#pragma unroll
            for (int ct = 0; ct < 4; ++ct) {
                const size_t pi = (size_t)(((kc * 8 + T) * 8 + cw * 4 + ct) * 64 + lane) * 8;
                short8 bh = *(const short8*)(wh + pi);
                short8 bl = *(const short8*)(wl + pi);
                acc[ct] = MFMA32(bh, ahi[T], acc[ct]);
                acc[ct] = MFMA32(bl, ahi[T], acc[ct]);
                acc[ct] = MFMA32(bh, alo[T], acc[ct]);
            }
    }

    float s1 = 0.f, s2 = 0.f;
#pragma unroll
    for (int ct = 0; ct < 4; ++ct)
#pragma unroll
        for (int g = 0; g < 4; ++g) {
            const int c0 = cw * 128 + ct * 32 + g * 8 + lh * 4;
            float4 bz = *(const float4*)(b1 + c0);
            float bzf[4] = {bz.x, bz.y, bz.z, bz.w};
#pragma unroll
            for (int j2 = 0; j2 < 4; ++j2) {
                acc[ct][g * 4 + j2] += bzf[j2];
                s1 += acc[ct][g * 4 + j2];
                s2 += acc[ct][g * 4 + j2] * acc[ct][g * 4 + j2];
            }
        }
    s1 += __shfl_xor(s1, 32);
    s2 += __shfl_xor(s2, 32);
    if (lh == 0) { s1buf[rw][l31][cw] = s1; s2buf[rw][l31][cw] = s2; }
    __syncthreads();
    float s1t = s1buf[rw][l31][0] + s1buf[rw][l31][1];
    float s2t = s2buf[rw][l31][0] + s2buf[rw][l31][1];
    float mu = s1t * (1.0f / HDIM);
    float var = s2t * (1.0f / HDIM) - mu * mu;
    float inv = 1.0f / sqrtf(var + 1e-5f);

#pragma unroll
    for (int ct = 0; ct < 4; ++ct)
#pragma unroll
        for (int g = 0; g < 4; ++g) {
            const int c0 = cw * 128 + ct * 32 + g * 8 + lh * 4;
            float4 gg = *(const float4*)(lng + c0);
            float4 bb = *(const float4*)(lnb + c0);
            float ggf[4] = {gg.x, gg.y, gg.z, gg.w};
            float bbf[4] = {bb.x, bb.y, bb.z, bb.w};
            short4v hv, lv;
#pragma unroll
            for (int j2 = 0; j2 < 4; ++j2) {
                float hval = (acc[ct][g * 4 + j2] - mu) * inv * ggf[j2] + bbf[j2];
                float gval = hval / (1.0f + expf(-hval));
                unsigned short h = f2bf(gval);
                hv[j2] = (short)h;
                lv[j2] = (short)f2bf(gval - bf2f(h));
            }
            *(short4v*)(gh + (size_t)row * HDIM + c0) = hv;
            *(short4v*)(gl + (size_t)row * HDIM + c0) = lv;
        }
}

// ---------------- MFMA update GEMM (unchanged) ----------------
__global__ __launch_bounds__(256, 2)
void gemm_upd_mfma(const unsigned short* __restrict__ gh, const unsigned short* __restrict__ gl,
                   const unsigned short* __restrict__ wh, const unsigned short* __restrict__ wl,
                   const float* __restrict__ b2, float* __restrict__ state) {
    const int tid = threadIdx.x, lane = tid & 63, w = tid >> 6;
    const int l31 = lane & 31, lh = lane >> 5;
    const int rw = w & 1, cw = w >> 1;
    const int row = blockIdx.x * 64 + rw * 32 + l31;

    f32x16 acc[2];
#pragma unroll
    for (int ct = 0; ct < 2; ++ct)
#pragma unroll
        for (int r = 0; r < 16; ++r) acc[ct][r] = 0.f;

    short8 ahi[8], alo[8];
#pragma unroll
    for (int kc = 0; kc < 2; ++kc) {
#pragma unroll
        for (int T = 0; T < 8; ++T) {
            ahi[T] = *(const short8*)(gh + (size_t)row * HDIM + kc * 128 + T * 16 + lh * 8);
            alo[T] = *(const short8*)(gl + (size_t)row * HDIM + kc * 128 + T * 16 + lh * 8);
        }
#pragma unroll
        for (int T = 0; T < 8; ++T)
#pragma unroll
            for (int ct = 0; ct < 2; ++ct) {
                const size_t pi = (size_t)(((kc * 8 + T) * 4 + cw * 2 + ct) * 64 + lane) * 8;
                short8 bh = *(const short8*)(wh + pi);
                short8 bl = *(const short8*)(wl + pi);
                acc[ct] = MFMA32(bh, ahi[T], acc[ct]);
                acc[ct] = MFMA32(bl, ahi[T], acc[ct]);
                acc[ct] = MFMA32(bh, alo[T], acc[ct]);
            }
    }

#pragma unroll
    for (int ct = 0; ct < 2; ++ct)
#pragma unroll
        for (int g = 0; g < 4; ++g) {
            const int c0 = cw * 64 + ct * 32 + g * 8 + lh * 4;
            float4 bz = *(const float4*)(b2 + c0);
            float bzf[4] = {bz.x, bz.y, bz.z, bz.w};
            float4* sp = (float4*)(state + (size_t)row * DDIM + c0);
            float4 sv = *sp;
            float svf[4] = {sv.x, sv.y, sv.z, sv.w};
#pragma unroll
            for (int j2 = 0; j2 < 4; ++j2) svf[j2] += acc[ct][g * 4 + j2] + bzf[j2];
            sv.x = svf[0]; sv.y = svf[1]; sv.z = svf[2]; sv.w = svf[3];
            *sp = sv;
        }
}

// ---------------- final reduction (unchanged) ----------------
__global__ void partial_mean_kernel(const float* __restrict__ state, float* __restrict__ partial) {
    int b = blockIdx.y, seg = blockIdx.x, tid = threadIdx.x;
    const float* sp = state + ((size_t)b * NN + (size_t)seg * 128) * DDIM;
    float acc = 0.f;
    for (int i = 0; i < 128; ++i) acc += sp[(size_t)i * DDIM + tid];
    partial[((size_t)b * 32 + seg) * DDIM + tid] = acc;
}

__global__ void final_out_kernel(const float* __restrict__ partial, const float* __restrict__ Wo,
                                 const float* __restrict__ bo, float* __restrict__ out) {
    __shared__ float mean[BQ][DDIM];
    int tid = threadIdx.x;
    for (int o = tid; o < BQ * DDIM; o += 256) {
        int b = o >> 7, d = o & 127;
        float s = 0.f;
        for (int p = 0; p < 32; ++p) s += partial[((size_t)b * 32 + p) * DDIM + d];
        mean[b][d] = s * (1.0f / NN);
    }
    __syncthreads();
    for (int o = tid; o < BQ * DDIM; o += 256) {
        int b = o >> 7, c = o & 127;
        float acc = bo[c];
        for (int d = 0; d < DDIM; ++d) acc += mean[b][d] * Wo[d * DDIM + c];
        out[o] = acc;
    }
}

extern "C" void kernel_launch(void* const* d_in, const int* in_sizes, int n_in,
                              void* d_out, int out_size, void* d_ws, size_t ws_size,
                              hipStream_t stream) {
    const float* x   = (const float*)d_in[0];
    const float* Wn  = (const float*)d_in[1];
    const float* bn  = (const float*)d_in[2];
    const float* W1  = (const float*)d_in[3];
    const float* b1  = (const float*)d_in[4];
    const float* lng = (const float*)d_in[5];
    const float* lnb = (const float*)d_in[6];
    const float* W2  = (const float*)d_in[7];
    const float* b2  = (const float*)d_in[8];
    const float* Wo  = (const float*)d_in[9];
    const float* bo  = (const float*)d_in[10];
    float* out = (float*)d_out;

    float* ws    = (float*)d_ws;
    float* state = ws;
    unsigned short* agghi = (unsigned short*)(state + (size_t)RTOT * DDIM);
    unsigned short* agglo = agghi + (size_t)RTOT * HDIM;
    unsigned short* khi_b = agglo + (size_t)RTOT * HDIM;
    unsigned short* klo_b = khi_b + (size_t)RTOT * HDIM;
    unsigned short* ghi = khi_b;                               // alias (khi dead after sim)
    unsigned short* glo = klo_b;                               // alias (klo dead after sim)
    float* partial = (float*)(klo_b + (size_t)RTOT * HDIM);
    float* svals   = partial + (size_t)BQ * 32 * DDIM;         // RTOT*16 f32
    int*   sidx    = (int*)(svals + (size_t)RTOT * 16);        // RTOT*16 i32
    unsigned short* wnh = (unsigned short*)(sidx + (size_t)RTOT * 16);
    unsigned short* wnl = wnh + 128 * 256;
    unsigned short* w1h = wnl + 128 * 256;
    unsigned short* w1l = w1h + 384 * 256;
    unsigned short* w2h = w1l + 384 * 256;
    unsigned short* w2l = w2h + 256 * 128;

    hipMemcpyAsync(state, x, (size_t)RTOT * DDIM * sizeof(float),
                   hipMemcpyDeviceToDevice, stream);

    pack_w_kernel<<<(128 / 16) * (256 / 32), 64, 0, stream>>>(Wn, 256, wnh, wnl);
    pack_w_kernel<<<(384 / 16) * (256 / 32), 64, 0, stream>>>(W1, 256, w1h, w1l);
    pack_w_kernel<<<(256 / 16) * (128 / 32), 64, 0, stream>>>(W2, 128, w2h, w2l);

    for (int step = 0; step < 3; ++step) {
        gemm_keys_mfma<<<RTOT / 64, 256, 0, stream>>>(state, wnh, wnl, bn, khi_b, klo_b);
        sim_topk_kernel<<<1024, 256, 0, stream>>>(khi_b, klo_b, svals, sidx);
        gemm_agg_mfma<<<RTOT / 64, 256, 0, stream>>>(state, svals, sidx, wnh, wnl, bn,
                                                     agghi, agglo);
        gemm_ln_mfma<<<RTOT / 64, 256, 0, stream>>>(state, agghi, agglo, w1h, w1l,
                                                    b1, lng, lnb, ghi, glo);
        gemm_upd_mfma<<<RTOT / 64, 256, 0, stream>>>(ghi, glo, w2h, w2l, b2, state);
    }
    partial_mean_kernel<<<dim3(32, BQ), 128, 0, stream>>>(state, partial);
    final_out_kernel<<<1, 256, 0, stream>>>(partial, Wo, bo, out);
}

// Round 15
// 833.468 us; speedup vs baseline: 1.5854x; 1.2416x over previous
//
#include <hip/hip_runtime.h>

#define DDIM 128
#define HDIM 256
#define BQ   4
#define NN   4096
#define RTOT (BQ*NN)

typedef short short8 __attribute__((ext_vector_type(8)));
typedef short short4v __attribute__((ext_vector_type(4)));
typedef float f32x16 __attribute__((ext_vector_type(16)));

__device__ inline unsigned short f2bf(float f) {
    unsigned int u = __float_as_uint(f);
    unsigned int r = (u + 0x7fffu + ((u >> 16) & 1u)) >> 16;
    return (unsigned short)r;
}
__device__ inline float bf2f(unsigned short h) {
    return __uint_as_float(((unsigned int)h) << 16);
}

#define MFMA32(a, b, c) __builtin_amdgcn_mfma_f32_32x32x16_bf16(a, b, c, 0, 0, 0)

// ---------------- weight packer (unchanged) ----------------
__global__ void pack_w_kernel(const float* __restrict__ W, int N,
                              unsigned short* __restrict__ ph, unsigned short* __restrict__ pl) {
    int l = threadIdx.x, l31 = l & 31, lh = l >> 5;
    int nt = N >> 5;
    int t = blockIdx.x / nt, c = blockIdx.x % nt;
    short8 hv, lv;
#pragma unroll
    for (int j = 0; j < 8; ++j) {
        float f = W[(size_t)(t * 16 + lh * 8 + j) * N + c * 32 + l31];
        unsigned short h = f2bf(f);
        hv[j] = (short)h;
        lv[j] = (short)f2bf(f - bf2f(h));
    }
    *(short8*)(ph + (size_t)(blockIdx.x * 64 + l) * 8) = hv;
    *(short8*)(pl + (size_t)(blockIdx.x * 64 + l) * 8) = lv;
}

// ---------------- fused sim + top-8: round-11 structure (best, 193us) + saddr addressing ----
// grid 512 (2 blocks/CU), block 256 = 4 waves. Block = 32 rows x 4096 cols. 4 bufs x 4KB/wave,
// prefetch depth 3, vmcnt(8)/lgkmcnt(4), conflict-free key (l31>>1)&3 -- all round-11-proven.
// NEW: DMA source = (scalar base + step offset) + loop-invariant 32-bit lane offset, so the
// compiler emits saddr-form global_load_lds (SALU-only per-step address updates). Round-11
// computed mixed uniform*divergent products per step (~50 VALU/step, VALUBusy 40% > MFMA).
__global__ __launch_bounds__(256, 2)
void sim_topk_kernel(const unsigned short* __restrict__ khi,
                     const unsigned short* __restrict__ klo,
                     int* __restrict__ idxout) {
    __shared__ __align__(16) char smem[4 * 4 * 4096];   // 4 waves x 4 bufs x 4KB

    const int id = blockIdx.x;
    const int xcd = id & 7;
    const int b = xcd >> 1;
    const int j = ((id >> 3) << 1) | (xcd & 1);
    const int rowbase = j * 32;
    const unsigned short* khiB = khi + (size_t)b * NN * HDIM;
    const unsigned short* kloB = klo + (size_t)b * NN * HDIM;

    const int tid = threadIdx.x;
    const int lane = tid & 63, w = tid >> 6;
    const int l31 = lane & 31, lh = lane >> 5;

    short8 ah[16], al[16];
    {
        const unsigned short* ph = khiB + (size_t)(rowbase + l31) * HDIM + lh * 8;
        const unsigned short* pl = kloB + (size_t)(rowbase + l31) * HDIM + lh * 8;
#pragma unroll
        for (int T = 0; T < 16; ++T) {
            ah[T] = *(const short8*)(ph + T * 16);
            al[T] = *(const short8*)(pl + T * 16);
        }
    }
#pragma unroll
    for (int T = 0; T < 16; ++T) {
        asm volatile("" : "+v"(ah[T]));
        asm volatile("" : "+v"(al[T]));
    }

    char* mybuf = smem + w * 16384;

    // lane-invariant 32-bit offsets (divergent); step part stays scalar -> saddr form.
    const int sc = lane >> 2, sg = lane & 3;
    const int ssw = (sg ^ ((sc >> 1) & 3)) * 8;
    const int laneOff0 = (w * 1024 + sc) * HDIM + ssw;        // i = 0 (cols +0..15)
    const int laneOff1 = (w * 1024 + 16 + sc) * HDIM + ssw;   // i = 1 (cols +16..31)

    auto stage = [&](int s) {
        const int stepOff = (s >> 3) * 32 * HDIM + (s & 7) * 32;   // scalar (loop-derived)
        const unsigned short* baseH = khiB + stepOff;
        const unsigned short* baseL = kloB + stepOff;
        char* dst = mybuf + (s & 3) * 4096;
        __builtin_amdgcn_global_load_lds(
            (const __attribute__((address_space(1))) void*)(baseH + laneOff0),
            (__attribute__((address_space(3))) void*)(dst), 16, 0, 0);
        __builtin_amdgcn_global_load_lds(
            (const __attribute__((address_space(1))) void*)(baseH + laneOff1),
            (__attribute__((address_space(3))) void*)(dst + 1024), 16, 0, 0);
        __builtin_amdgcn_global_load_lds(
            (const __attribute__((address_space(1))) void*)(baseL + laneOff0),
            (__attribute__((address_space(3))) void*)(dst + 2048), 16, 0, 0);
        __builtin_amdgcn_global_load_lds(
            (const __attribute__((address_space(1))) void*)(baseL + laneOff1),
            (__attribute__((address_space(3))) void*)(dst + 3072), 16, 0, 0);
    };

    stage(0);
    stage(1);
    stage(2);

    const int key = (l31 >> 1) & 3;
    const int rb0 = l31 * 64 + ((lh ^ key) * 16);
    const int rb1 = l31 * 64 + (((2 + lh) ^ key) * 16);

    float tv[8]; int ti[8];
#pragma unroll
    for (int s = 0; s < 8; ++s) { tv[s] = -1e30f; ti[s] = 0x7fffffff; }

    for (int cs = 0; cs < 32; ++cs) {
        f32x16 acc;
#pragma unroll
        for (int r = 0; r < 16; ++r) acc[r] = 0.f;

#pragma unroll
        for (int ks = 0; ks < 8; ++ks) {
            const int s = cs * 8 + ks;
            if (s < 254)       asm volatile("s_waitcnt vmcnt(8)" ::: "memory");
            else if (s == 254) asm volatile("s_waitcnt vmcnt(4)" ::: "memory");
            else               asm volatile("s_waitcnt vmcnt(0)" ::: "memory");

            const char* bufc = mybuf + (s & 3) * 4096;
            short8 Bh0 = *(const short8*)(bufc + rb0);
            short8 Bl0 = *(const short8*)(bufc + 2048 + rb0);
            short8 Bh1 = *(const short8*)(bufc + rb1);
            short8 Bl1 = *(const short8*)(bufc + 2048 + rb1);
            asm volatile("s_waitcnt lgkmcnt(4)" ::: "memory");
            if (s + 3 < 256) stage(s + 3);

            const int T0 = ks * 2, T1 = ks * 2 + 1;
            acc = MFMA32(Bh0, ah[T0], acc);
            acc = MFMA32(Bh0, al[T0], acc);
            acc = MFMA32(Bl0, ah[T0], acc);
            acc = MFMA32(Bh1, ah[T1], acc);
            acc = MFMA32(Bh1, al[T1], acc);
            acc = MFMA32(Bl1, ah[T1], acc);
        }

        const int cbase = w * 1024 + cs * 32 + 4 * lh;
#pragma unroll
        for (int r = 0; r < 16; ++r) {
            float v = acc[r];
            int col = cbase + (r & 3) + 8 * (r >> 2);
            if (v > tv[7]) {
                tv[7] = v; ti[7] = col;
#pragma unroll
                for (int q = 7; q >= 1; --q) {
                    if (tv[q] > tv[q - 1]) {
                        float a0 = tv[q]; tv[q] = tv[q - 1]; tv[q - 1] = a0;
                        int   c0_ = ti[q]; ti[q] = ti[q - 1]; ti[q - 1] = c0_;
                    }
                }
            }
        }
    }

    __syncthreads();
    float* vbuf = (float*)smem;
    int*   ibuf = (int*)(smem + 32 * 66 * 4);
    const int list = w * 2 + lh;
#pragma unroll
    for (int s = 0; s < 8; ++s) {
        vbuf[l31 * 66 + list * 8 + s] = tv[s];
        ibuf[l31 * 66 + list * 8 + s] = ti[s];
    }
    __syncthreads();
    if (tid < 32) {
        float fv[8]; int fi[8];
#pragma unroll
        for (int s = 0; s < 8; ++s) { fv[s] = -1e30f; fi[s] = 0x7fffffff; }
        for (int e = 0; e < 64; ++e) {
            float v = vbuf[tid * 66 + e];
            int  ix = ibuf[tid * 66 + e];
            bool ins = (v > fv[7]) || (v == fv[7] && ix < fi[7]);
            if (ins) {
                fv[7] = v; fi[7] = ix;
#pragma unroll
                for (int q = 7; q >= 1; --q) {
                    bool sw = (fv[q] > fv[q - 1]) || (fv[q] == fv[q - 1] && fi[q] < fi[q - 1]);
                    if (sw) {
                        float a0 = fv[q]; fv[q] = fv[q - 1]; fv[q - 1] = a0;
                        int   c0_ = fi[q]; fi[q] = fi[q - 1]; fi[q - 1] = c0_;
                    }
                }
            }
        }
        size_t basei = ((size_t)b * NN + rowbase + tid) * 8;
#pragma unroll
        for (int s = 0; s < 8; ++s) idxout[basei + s] = fi[s];
    }
}

// ---------------- MFMA keys GEMM + normalize (unchanged, working) ----------------
__global__ __launch_bounds__(256, 2)
void gemm_keys_mfma(const float* __restrict__ A,
                    const unsigned short* __restrict__ wh, const unsigned short* __restrict__ wl,
                    const float* __restrict__ bias,
                    unsigned short* __restrict__ khi, unsigned short* __restrict__ klo) {
    __shared__ float ssqbuf[2][32][2];
    const int tid = threadIdx.x, lane = tid & 63, w = tid >> 6;
    const int l31 = lane & 31, lh = lane >> 5;
    const int rw = w & 1, cw = w >> 1;
    const int row = blockIdx.x * 64 + rw * 32 + l31;

    short8 ahi[8], alo[8];
    const float* ap = A + (size_t)row * DDIM + lh * 8;
#pragma unroll
    for (int T = 0; T < 8; ++T) {
        float4 f0 = *(const float4*)(ap + T * 16);
        float4 f1 = *(const float4*)(ap + T * 16 + 4);
        float ff[8] = {f0.x, f0.y, f0.z, f0.w, f1.x, f1.y, f1.z, f1.w};
#pragma unroll
        for (int j2 = 0; j2 < 8; ++j2) {
            unsigned short h = f2bf(ff[j2]);
            ahi[T][j2] = (short)h;
            alo[T][j2] = (short)f2bf(ff[j2] - bf2f(h));
        }
    }

    f32x16 acc[4];
#pragma unroll
    for (int ct = 0; ct < 4; ++ct)
#pragma unroll
        for (int r = 0; r < 16; ++r) acc[ct][r] = 0.f;

#pragma unroll
    for (int T = 0; T < 8; ++T) {
#pragma unroll
        for (int ct = 0; ct < 4; ++ct) {
            const size_t pi = (size_t)((T * 8 + cw * 4 + ct) * 64 + lane) * 8;
            short8 bh = *(const short8*)(wh + pi);
            short8 bl = *(const short8*)(wl + pi);
            acc[ct] = MFMA32(bh, ahi[T], acc[ct]);
            acc[ct] = MFMA32(bl, ahi[T], acc[ct]);
            acc[ct] = MFMA32(bh, alo[T], acc[ct]);
        }
    }

    float ss = 0.f;
#pragma unroll
    for (int ct = 0; ct < 4; ++ct)
#pragma unroll
        for (int g = 0; g < 4; ++g) {
            const int c0 = cw * 128 + ct * 32 + g * 8 + lh * 4;
            float4 bz = *(const float4*)(bias + c0);
            float bzf[4] = {bz.x, bz.y, bz.z, bz.w};
#pragma unroll
            for (int j2 = 0; j2 < 4; ++j2) {
                acc[ct][g * 4 + j2] += bzf[j2];
                ss += acc[ct][g * 4 + j2] * acc[ct][g * 4 + j2];
            }
        }
    ss += __shfl_xor(ss, 32);
    if (lh == 0) ssqbuf[rw][l31][cw] = ss;
    __syncthreads();
    float sstot = ssqbuf[rw][l31][0] + ssqbuf[rw][l31][1];
    float scn = 1.0f / fmaxf(sqrtf(sstot), 1e-12f);

#pragma unroll
    for (int ct = 0; ct < 4; ++ct)
#pragma unroll
        for (int g = 0; g < 4; ++g) {
            const int c0 = cw * 128 + ct * 32 + g * 8 + lh * 4;
            short4v hv, lv;
#pragma unroll
            for (int j2 = 0; j2 < 4; ++j2) {
                float vn = acc[ct][g * 4 + j2] * scn;
                unsigned short h = f2bf(vn);
                hv[j2] = (short)h;
                lv[j2] = (short)f2bf(vn - bf2f(h));
            }
            *(short4v*)(khi + (size_t)row * HDIM + c0) = hv;
            *(short4v*)(klo + (size_t)row * HDIM + c0) = lv;
        }
}

// ---------------- MFMA agg GEMM (round-11 version, separate gather) ----------------
__global__ __launch_bounds__(256, 2)
void gemm_agg_mfma(const float* __restrict__ A,
                   const unsigned short* __restrict__ wh, const unsigned short* __restrict__ wl,
                   const float* __restrict__ bias,
                   unsigned short* __restrict__ oh, unsigned short* __restrict__ ol) {
    const int tid = threadIdx.x, lane = tid & 63, w = tid >> 6;
    const int l31 = lane & 31, lh = lane >> 5;
    const int rw = w & 1, cw = w >> 1;
    const int row = blockIdx.x * 64 + rw * 32 + l31;

    short8 ahi[8], alo[8];
    const float* ap = A + (size_t)row * DDIM + lh * 8;
#pragma unroll
    for (int T = 0; T < 8; ++T) {
        float4 f0 = *(const float4*)(ap + T * 16);
        float4 f1 = *(const float4*)(ap + T * 16 + 4);
        float ff[8] = {f0.x, f0.y, f0.z, f0.w, f1.x, f1.y, f1.z, f1.w};
#pragma unroll
        for (int j2 = 0; j2 < 8; ++j2) {
            unsigned short h = f2bf(ff[j2]);
            ahi[T][j2] = (short)h;
            alo[T][j2] = (short)f2bf(ff[j2] - bf2f(h));
        }
    }

    f32x16 acc[4];
#pragma unroll
    for (int ct = 0; ct < 4; ++ct)
#pragma unroll
        for (int r = 0; r < 16; ++r) acc[ct][r] = 0.f;

#pragma unroll
    for (int T = 0; T < 8; ++T) {
#pragma unroll
        for (int ct = 0; ct < 4; ++ct) {
            const size_t pi = (size_t)((T * 8 + cw * 4 + ct) * 64 + lane) * 8;
            short8 bh = *(const short8*)(wh + pi);
            short8 bl = *(const short8*)(wl + pi);
            acc[ct] = MFMA32(bh, ahi[T], acc[ct]);
            acc[ct] = MFMA32(bl, ahi[T], acc[ct]);
            acc[ct] = MFMA32(bh, alo[T], acc[ct]);
        }
    }

#pragma unroll
    for (int ct = 0; ct < 4; ++ct)
#pragma unroll
        for (int g = 0; g < 4; ++g) {
            const int c0 = cw * 128 + ct * 32 + g * 8 + lh * 4;
            float4 bz = *(const float4*)(bias + c0);
            float bzf[4] = {bz.x, bz.y, bz.z, bz.w};
            short4v hv, lv;
#pragma unroll
            for (int j2 = 0; j2 < 4; ++j2) {
                float vn = acc[ct][g * 4 + j2] + bzf[j2];
                unsigned short h = f2bf(vn);
                hv[j2] = (short)h;
                lv[j2] = (short)f2bf(vn - bf2f(h));
            }
            *(short4v*)(oh + (size_t)row * HDIM + c0) = hv;
            *(short4v*)(ol + (size_t)row * HDIM + c0) = lv;
        }
}

// ---------------- gather top-8 rows + mean (round-11 version) ----------------
__global__ void gather_mean_kernel(const float* __restrict__ state, const int* __restrict__ idx,
                                   float* __restrict__ M) {
    __shared__ int ilds[16];
    int tid = threadIdx.x;
    int row0 = blockIdx.x * 2;
    if (tid < 16) ilds[tid] = idx[(size_t)row0 * 8 + tid];
    __syncthreads();
    int lr = tid >> 7, d = tid & 127;
    int grow = row0 + lr;
    int b = grow >> 12;
    const float* sb = state + (size_t)b * NN * DDIM;
    float acc = 0.f;
#pragma unroll
    for (int k = 0; k < 8; ++k) acc += sb[(size_t)ilds[lr * 8 + k] * DDIM + d];
    M[(size_t)grow * DDIM + d] = acc * 0.125f;
}

// ---------------- MFMA concat GEMM (K=384) + LN + silu (unchanged) ----------------
__global__ __launch_bounds__(256, 2)
void gemm_ln_mfma(const float* __restrict__ state,
                  const unsigned short* __restrict__ agh, const unsigned short* __restrict__ agl,
                  const unsigned short* __restrict__ wh, const unsigned short* __restrict__ wl,
                  const float* __restrict__ b1, const float* __restrict__ lng,
                  const float* __restrict__ lnb,
                  unsigned short* __restrict__ gh, unsigned short* __restrict__ gl) {
    __shared__ float s1buf[2][32][2], s2buf[2][32][2];
    const int tid = threadIdx.x, lane = tid & 63, w = tid >> 6;
    const int l31 = lane & 31, lh = lane >> 5;
    const int rw = w & 1, cw = w >> 1;
    const int row = blockIdx.x * 64 + rw * 32 + l31;

    f32x16 acc[4];
#pragma unroll
    for (int ct = 0; ct < 4; ++ct)
#pragma unroll
        for (int r = 0; r < 16; ++r) acc[ct][r] = 0.f;

    short8 ahi[8], alo[8];
    {
        const float* ap = state + (size_t)row * DDIM + lh * 8;
#pragma unroll
        for (int T = 0; T < 8; ++T) {
            float4 f0 = *(const float4*)(ap + T * 16);
            float4 f1 = *(const float4*)(ap + T * 16 + 4);
            float ff[8] = {f0.x, f0.y, f0.z, f0.w, f1.x, f1.y, f1.z, f1.w};
#pragma unroll
            for (int j2 = 0; j2 < 8; ++j2) {
                unsigned short h = f2bf(ff[j2]);
                ahi[T][j2] = (short)h;
                alo[T][j2] = (short)f2bf(ff[j2] - bf2f(h));
            }
        }
#pragma unroll
        for (int T = 0; T < 8; ++T)
#pragma unroll
            for (int ct = 0; ct < 4; ++ct) {
                const size_t pi = (size_t)((T * 8 + cw * 4 + ct) * 64 + lane) * 8;
                short8 bh = *(const short8*)(wh + pi);
                short8 bl = *(const short8*)(wl + pi);
                acc[ct] = MFMA32(bh, ahi[T], acc[ct]);
                acc[ct] = MFMA32(bl, ahi[T], acc[ct]);
                acc[ct] = MFMA32(bh, alo[T], acc[ct]);
            }
    }
#pragma unroll
    for (int kc = 1; kc < 3; ++kc) {
#pragma unroll
        for (int T = 0; T < 8; ++T) {
            ahi[T] = *(const short8*)(agh + (size_t)row * HDIM + (kc - 1) * 128 + T * 16 + lh * 8);
            alo[T] = *(const short8*)(agl + (size_t)row * HDIM + (kc - 1) * 128 + T * 16 + lh * 8);
        }
#pragma unroll
        for (int T = 0; T < 8; ++T)
#pragma unroll
            for (int ct = 0; ct < 4; ++ct) {
                const size_t pi = (size_t)(((kc * 8 + T) * 8 + cw * 4 + ct) * 64 + lane) * 8;
                short8 bh = *(const short8*)(wh + pi);
                short8 bl = *(const short8*)(wl + pi);
                acc[ct] = MFMA32(bh, ahi[T], acc[ct]);
                acc[ct] = MFMA32(bl, ahi[T], acc[ct]);
                acc[ct] = MFMA32(bh, alo[T], acc[ct]);
            }
    }

    float s1 = 0.f, s2 = 0.f;
#pragma unroll
    for (int ct = 0; ct < 4; ++ct)
#pragma unroll
        for (int g = 0; g < 4; ++g) {
            const int c0 = cw * 128 + ct * 32 + g * 8 + lh * 4;
            float4 bz = *(const float4*)(b1 + c0);
            float bzf[4] = {bz.x, bz.y, bz.z, bz.w};
#pragma unroll
            for (int j2 = 0; j2 < 4; ++j2) {
                acc[ct][g * 4 + j2] += bzf[j2];
                s1 += acc[ct][g * 4 + j2];
                s2 += acc[ct][g * 4 + j2] * acc[ct][g * 4 + j2];
            }
        }
    s1 += __shfl_xor(s1, 32);
    s2 += __shfl_xor(s2, 32);
    if (lh == 0) { s1buf[rw][l31][cw] = s1; s2buf[rw][l31][cw] = s2; }
    __syncthreads();
    float s1t = s1buf[rw][l31][0] + s1buf[rw][l31][1];
    float s2t = s2buf[rw][l31][0] + s2buf[rw][l31][1];
    float mu = s1t * (1.0f / HDIM);
    float var = s2t * (1.0f / HDIM) - mu * mu;
    float inv = 1.0f / sqrtf(var + 1e-5f);

#pragma unroll
    for (int ct = 0; ct < 4; ++ct)
#pragma unroll
        for (int g = 0; g < 4; ++g) {
            const int c0 = cw * 128 + ct * 32 + g * 8 + lh * 4;
            float4 gg = *(const float4*)(lng + c0);
            float4 bb = *(const float4*)(lnb + c0);
            float ggf[4] = {gg.x, gg.y, gg.z, gg.w};
            float bbf[4] = {bb.x, bb.y, bb.z, bb.w};
            short4v hv, lv;
#pragma unroll
            for (int j2 = 0; j2 < 4; ++j2) {
                float hval = (acc[ct][g * 4 + j2] - mu) * inv * ggf[j2] + bbf[j2];
                float gval = hval / (1.0f + expf(-hval));
                unsigned short h = f2bf(gval);
                hv[j2] = (short)h;
                lv[j2] = (short)f2bf(gval - bf2f(h));
            }
            *(short4v*)(gh + (size_t)row * HDIM + c0) = hv;
            *(short4v*)(gl + (size_t)row * HDIM + c0) = lv;
        }
}

// ---------------- MFMA update GEMM (unchanged) ----------------
__global__ __launch_bounds__(256, 2)
void gemm_upd_mfma(const unsigned short* __restrict__ gh, const unsigned short* __restrict__ gl,
                   const unsigned short* __restrict__ wh, const unsigned short* __restrict__ wl,
                   const float* __restrict__ b2, float* __restrict__ state) {
    const int tid = threadIdx.x, lane = tid & 63, w = tid >> 6;
    const int l31 = lane & 31, lh = lane >> 5;
    const int rw = w & 1, cw = w >> 1;
    const int row = blockIdx.x * 64 + rw * 32 + l31;

    f32x16 acc[2];
#pragma unroll
    for (int ct = 0; ct < 2; ++ct)
#pragma unroll
        for (int r = 0; r < 16; ++r) acc[ct][r] = 0.f;

    short8 ahi[8], alo[8];
#pragma unroll
    for (int kc = 0; kc < 2; ++kc) {
#pragma unroll
        for (int T = 0; T < 8; ++T) {
            ahi[T] = *(const short8*)(gh + (size_t)row * HDIM + kc * 128 + T * 16 + lh * 8);
            alo[T] = *(const short8*)(gl + (size_t)row * HDIM + kc * 128 + T * 16 + lh * 8);
        }
#pragma unroll
        for (int T = 0; T < 8; ++T)
#pragma unroll
            for (int ct = 0; ct < 2; ++ct) {
                const size_t pi = (size_t)(((kc * 8 + T) * 4 + cw * 2 + ct) * 64 + lane) * 8;
                short8 bh = *(const short8*)(wh + pi);
                short8 bl = *(const short8*)(wl + pi);
                acc[ct] = MFMA32(bh, ahi[T], acc[ct]);
                acc[ct] = MFMA32(bl, ahi[T], acc[ct]);
                acc[ct] = MFMA32(bh, alo[T], acc[ct]);
            }
    }

#pragma unroll
    for (int ct = 0; ct < 2; ++ct)
#pragma unroll
        for (int g = 0; g < 4; ++g) {
            const int c0 = cw * 64 + ct * 32 + g * 8 + lh * 4;
            float4 bz = *(const float4*)(b2 + c0);
            float bzf[4] = {bz.x, bz.y, bz.z, bz.w};
            float4* sp = (float4*)(state + (size_t)row * DDIM + c0);
            float4 sv = *sp;
            float svf[4] = {sv.x, sv.y, sv.z, sv.w};
#pragma unroll
            for (int j2 = 0; j2 < 4; ++j2) svf[j2] += acc[ct][g * 4 + j2] + bzf[j2];
            sv.x = svf[0]; sv.y = svf[1]; sv.z = svf[2]; sv.w = svf[3];
            *sp = sv;
        }
}

// ---------------- final reduction (unchanged) ----------------
__global__ void partial_mean_kernel(const float* __restrict__ state, float* __restrict__ partial) {
    int b = blockIdx.y, seg = blockIdx.x, tid = threadIdx.x;
    const float* sp = state + ((size_t)b * NN + (size_t)seg * 128) * DDIM;
    float acc = 0.f;
    for (int i = 0; i < 128; ++i) acc += sp[(size_t)i * DDIM + tid];
    partial[((size_t)b * 32 + seg) * DDIM + tid] = acc;
}

__global__ void final_out_kernel(const float* __restrict__ partial, const float* __restrict__ Wo,
                                 const float* __restrict__ bo, float* __restrict__ out) {
    __shared__ float mean[BQ][DDIM];
    int tid = threadIdx.x;
    for (int o = tid; o < BQ * DDIM; o += 256) {
        int b = o >> 7, d = o & 127;
        float s = 0.f;
        for (int p = 0; p < 32; ++p) s += partial[((size_t)b * 32 + p) * DDIM + d];
        mean[b][d] = s * (1.0f / NN);
    }
    __syncthreads();
    for (int o = tid; o < BQ * DDIM; o += 256) {
        int b = o >> 7, c = o & 127;
        float acc = bo[c];
        for (int d = 0; d < DDIM; ++d) acc += mean[b][d] * Wo[d * DDIM + c];
        out[o] = acc;
    }
}

extern "C" void kernel_launch(void* const* d_in, const int* in_sizes, int n_in,
                              void* d_out, int out_size, void* d_ws, size_t ws_size,
                              hipStream_t stream) {
    const float* x   = (const float*)d_in[0];
    const float* Wn  = (const float*)d_in[1];
    const float* bn  = (const float*)d_in[2];
    const float* W1  = (const float*)d_in[3];
    const float* b1  = (const float*)d_in[4];
    const float* lng = (const float*)d_in[5];
    const float* lnb = (const float*)d_in[6];
    const float* W2  = (const float*)d_in[7];
    const float* b2  = (const float*)d_in[8];
    const float* Wo  = (const float*)d_in[9];
    const float* bo  = (const float*)d_in[10];
    float* out = (float*)d_out;

    float* ws    = (float*)d_ws;
    float* state = ws;
    unsigned short* agghi = (unsigned short*)(state + (size_t)RTOT * DDIM);
    unsigned short* agglo = agghi + (size_t)RTOT * HDIM;
    unsigned short* khi_b = agglo + (size_t)RTOT * HDIM;
    unsigned short* klo_b = khi_b + (size_t)RTOT * HDIM;
    float* Mbuf = (float*)khi_b;                               // alias (khi dead after sim)
    unsigned short* ghi = khi_b;                               // alias (Mbuf dead after agg)
    unsigned short* glo = klo_b;
    float* partial = (float*)(klo_b + (size_t)RTOT * HDIM);
    int*   idxbuf  = (int*)(partial + (size_t)BQ * 32 * DDIM);
    unsigned short* wnh = (unsigned short*)(idxbuf + (size_t)RTOT * 8);
    unsigned short* wnl = wnh + 128 * 256;
    unsigned short* w1h = wnl + 128 * 256;
    unsigned short* w1l = w1h + 384 * 256;
    unsigned short* w2h = w1l + 384 * 256;
    unsigned short* w2l = w2h + 256 * 128;

    hipMemcpyAsync(state, x, (size_t)RTOT * DDIM * sizeof(float),
                   hipMemcpyDeviceToDevice, stream);

    pack_w_kernel<<<(128 / 16) * (256 / 32), 64, 0, stream>>>(Wn, 256, wnh, wnl);
    pack_w_kernel<<<(384 / 16) * (256 / 32), 64, 0, stream>>>(W1, 256, w1h, w1l);
    pack_w_kernel<<<(256 / 16) * (128 / 32), 64, 0, stream>>>(W2, 128, w2h, w2l);

    for (int step = 0; step < 3; ++step) {
        gemm_keys_mfma<<<RTOT / 64, 256, 0, stream>>>(state, wnh, wnl, bn, khi_b, klo_b);
        sim_topk_kernel<<<512, 256, 0, stream>>>(khi_b, klo_b, idxbuf);
        gather_mean_kernel<<<RTOT / 2, 256, 0, stream>>>(state, idxbuf, Mbuf);
        gemm_agg_mfma<<<RTOT / 64, 256, 0, stream>>>(Mbuf, wnh, wnl, bn, agghi, agglo);
        gemm_ln_mfma<<<RTOT / 64, 256, 0, stream>>>(state, agghi, agglo, w1h, w1l,
                                                    b1, lng, lnb, ghi, glo);
        gemm_upd_mfma<<<RTOT / 64, 256, 0, stream>>>(ghi, glo, w2h, w2l, b2, state);
    }
    partial_mean_kernel<<<dim3(32, BQ), 128, 0, stream>>>(state, partial);
    final_out_kernel<<<1, 256, 0, stream>>>(partial, Wo, bo, out);
}